// Round 2
// baseline (2481.667 us; speedup 1.0000x reference)
//
#include <hip/hip_runtime.h>

typedef unsigned short u16;
typedef unsigned int   u32;
typedef float f32x4 __attribute__((ext_vector_type(4)));
typedef short bf16x8 __attribute__((ext_vector_type(8)));

#define DEV static __device__ __forceinline__

DEV u16 f2b(float f){
  u32 u = __builtin_bit_cast(u32, f);
  return (u16)((u + 0x7fffu + ((u >> 16) & 1u)) >> 16);
}
DEV float b2f(u16 h){ u32 u = ((u32)h) << 16; return __builtin_bit_cast(float, u); }
DEV u32 pack2(float a, float b){ return (u32)f2b(a) | ((u32)f2b(b) << 16); }
DEV uint4 pack8(const float* f){
  uint4 r; r.x = pack2(f[0],f[1]); r.y = pack2(f[2],f[3]);
  r.z = pack2(f[4],f[5]); r.w = pack2(f[6],f[7]); return r;
}
DEV void unpack8(uint4 u, float* f){
  f[0]=b2f((u16)(u.x&0xffffu)); f[1]=b2f((u16)(u.x>>16));
  f[2]=b2f((u16)(u.y&0xffffu)); f[3]=b2f((u16)(u.y>>16));
  f[4]=b2f((u16)(u.z&0xffffu)); f[5]=b2f((u16)(u.z>>16));
  f[6]=b2f((u16)(u.w&0xffffu)); f[7]=b2f((u16)(u.w>>16));
}
DEV float gelu_t(float x){
  return 0.5f*x*(1.f + tanhf(0.7978845608028654f*(x + 0.044715f*x*x*x)));
}

// ---------------- LayerNorm: fp32 [rows][1024] -> bf16 ----------------
__global__ __launch_bounds__(256)
void ln_k(const float* __restrict__ x, const float* __restrict__ gamma,
          const float* __restrict__ beta, u16* __restrict__ out)
{
  const int row = blockIdx.x;
  const int t = threadIdx.x;
  const float4 v = ((const float4*)(x + (size_t)row*1024))[t];
  float s  = v.x+v.y+v.z+v.w;
  float ss = v.x*v.x+v.y*v.y+v.z*v.z+v.w*v.w;
  #pragma unroll
  for (int o=32;o;o>>=1){ s += __shfl_xor(s,o); ss += __shfl_xor(ss,o); }
  __shared__ float rs[4], rq[4];
  if ((t&63)==0){ rs[t>>6]=s; rq[t>>6]=ss; }
  __syncthreads();
  s  = rs[0]+rs[1]+rs[2]+rs[3];
  ss = rq[0]+rq[1]+rq[2]+rq[3];
  const float mean = s*(1.f/1024.f);
  const float var  = ss*(1.f/1024.f) - mean*mean;
  const float inv  = rsqrtf(var + 1e-5f);
  const float4 g4 = ((const float4*)gamma)[t];
  const float4 b4 = ((const float4*)beta)[t];
  float o[4];
  o[0]=(v.x-mean)*inv*g4.x+b4.x; o[1]=(v.y-mean)*inv*g4.y+b4.y;
  o[2]=(v.z-mean)*inv*g4.z+b4.z; o[3]=(v.w-mean)*inv*g4.w+b4.w;
  uint2 w; w.x = pack2(o[0],o[1]); w.y = pack2(o[2],o[3]);
  *(uint2*)(out + (size_t)row*1024 + t*4) = w;
}

// ---------------- bf16 MFMA GEMM, 128x128 tile, BK=32 ----------------
#define EPI_BF16 0
#define EPI_WO   1
#define EPI_GELU 2
#define EPI_FF2  3

template<int EPI>
__global__ __launch_bounds__(256)
void gemm_k(const u16* __restrict__ A, const float* __restrict__ B,
            int K, int N, u16* __restrict__ obf, float* __restrict__ of32,
            const float* __restrict__ res, const float* __restrict__ bias)
{
  __shared__ __align__(16) u16 As[128][40];   // [m][k], pad
  __shared__ __align__(16) u16 Bs[128][40];   // B^T: [n][k]
  const int t = threadIdx.x;
  const int m0 = blockIdx.y << 7, n0 = blockIdx.x << 7;
  const int wave = t >> 6, lane = t & 63;
  const int wm = (wave >> 1) << 6, wn = (wave & 1) << 6;
  const int r16 = lane & 15, g = lane >> 4;
  const int arow = t >> 1, ak = (t & 1) << 4;
  const int bn = (t & 63) << 1, bk = (t >> 6) << 3;

  f32x4 acc[4][4];
  const f32x4 zz = {0.f,0.f,0.f,0.f};
  #pragma unroll
  for (int i=0;i<4;i++) { acc[i][0]=zz; acc[i][1]=zz; acc[i][2]=zz; acc[i][3]=zz; }

  for (int k0 = 0; k0 < K; k0 += 32){
    const uint4* ap = (const uint4*)(A + (size_t)(m0+arow)*K + k0 + ak);
    const uint4 a0 = ap[0], a1 = ap[1];
    const float* bp = B + (size_t)(k0+bk)*N + n0 + bn;
    float e0[8], e1[8];
    #pragma unroll
    for (int i=0;i<8;i++){
      const float2 f = *(const float2*)(bp + (size_t)i*N);
      e0[i]=f.x; e1[i]=f.y;
    }
    __syncthreads();
    *(uint4*)&As[arow][ak]   = a0;
    *(uint4*)&As[arow][ak+8] = a1;
    *(uint4*)&Bs[bn][bk]     = pack8(e0);
    *(uint4*)&Bs[bn+1][bk]   = pack8(e1);
    __syncthreads();
    bf16x8 af[4], bfv[4];
    #pragma unroll
    for (int i=0;i<4;i++) af[i]  = *(const bf16x8*)&As[wm + (i<<4) + r16][g<<3];
    #pragma unroll
    for (int j=0;j<4;j++) bfv[j] = *(const bf16x8*)&Bs[wn + (j<<4) + r16][g<<3];
    #pragma unroll
    for (int i=0;i<4;i++)
      #pragma unroll
      for (int j=0;j<4;j++)
        acc[i][j] = __builtin_amdgcn_mfma_f32_16x16x32_bf16(af[i], bfv[j], acc[i][j], 0,0,0);
  }

  #pragma unroll
  for (int i=0;i<4;i++){
    #pragma unroll
    for (int j=0;j<4;j++){
      const int gc = n0 + wn + (j<<4) + r16;
      #pragma unroll
      for (int r=0;r<4;r++){
        const int gr = m0 + wm + (i<<4) + (g<<2) + r;
        const size_t idx = (size_t)gr*N + gc;
        const float vv = acc[i][j][r];
        if (EPI==EPI_BF16)      obf[idx] = f2b(vv);
        else if (EPI==EPI_WO)   of32[idx] = res[idx] + vv;
        else if (EPI==EPI_GELU) obf[idx] = f2b(gelu_t(vv + bias[gc]));
        else                    of32[idx] = of32[idx] + vv + bias[gc];
      }
    }
  }
}

// ------------- per-segment memory contribution: Mseg, zseg -------------
__global__ __launch_bounds__(256)
void memseg_k(const u16* __restrict__ kb, const u16* __restrict__ vb,
              float* __restrict__ Mseg, float* __restrict__ zseg)
{
  const int bid = blockIdx.x;           // b*64 + h*8 + seg
  const int seg = bid & 7, h = (bid>>3)&7, b = bid>>6;
  __shared__ __align__(16) u16 ks[64][136];
  __shared__ __align__(16) u16 vs[64][136];
  const int t = threadIdx.x;
  const int srow = t>>2, sc = (t&3)<<3;
  const int ty = t>>4, tx = t&15;
  float acc[8][8];
  #pragma unroll
  for (int i=0;i<8;i++)
    #pragma unroll
    for (int j=0;j<8;j++) acc[i][j]=0.f;
  float zacc = 0.f;

  for (int s0=0; s0<512; s0+=64){
    __syncthreads();
    const size_t gr = ((size_t)b*4096 + seg*512 + s0 + srow)*1024 + h*128;
    #pragma unroll
    for (int i=0;i<4;i++){
      float f[8]; unpack8(*(const uint4*)(kb + gr + sc + i*32), f);
      #pragma unroll
      for (int e=0;e<8;e++) f[e] = f[e]>0.f ? f[e]+1.f : expf(f[e]); // elu+1
      *(uint4*)&ks[srow][sc + i*32] = pack8(f);
      *(uint4*)&vs[srow][sc + i*32] = *(const uint4*)(vb + gr + sc + i*32);
    }
    __syncthreads();
    for (int s=0;s<64;s++){
      float kf[8], vf[8];
      unpack8(*(const uint4*)&ks[s][ty<<3], kf);
      unpack8(*(const uint4*)&vs[s][tx<<3], vf);
      #pragma unroll
      for (int i=0;i<8;i++)
        #pragma unroll
        for (int j=0;j<8;j++) acc[i][j] += kf[i]*vf[j];
    }
    if (t < 128){
      for (int s=0;s<64;s++) zacc += b2f(ks[s][t]);
    }
  }
  const size_t mb = (size_t)bid*16384;
  #pragma unroll
  for (int i=0;i<8;i++)
    #pragma unroll
    for (int j=0;j<8;j++)
      Mseg[mb + (size_t)((ty<<3)+i)*128 + (tx<<3)+j] = acc[i][j];
  if (t < 128) zseg[(size_t)bid*128 + t] = zacc;
}

// ------------- prefix scan over segments -> memBefore, zBefore -------------
__global__ __launch_bounds__(256)
void scan_k(const float* __restrict__ Mseg, const float* __restrict__ zseg,
            u16* __restrict__ memB, float* __restrict__ zB)
{
  const int bh = blockIdx.x;   // b*8+h
  const int t = threadIdx.x;
  float run[64];
  #pragma unroll
  for (int i=0;i<64;i++) run[i]=0.f;
  for (int seg=0; seg<8; seg++){
    const size_t base = ((size_t)bh*8 + seg)*16384;
    #pragma unroll
    for (int i=0;i<64;i++) memB[base + t + i*256] = f2b(run[i]);
    #pragma unroll
    for (int i=0;i<64;i++) run[i] += Mseg[base + t + i*256];
  }
  if (t < 128){
    float zr = 1.f/128.f;
    for (int seg=0; seg<8; seg++){
      const size_t base = ((size_t)bh*8 + seg)*128;
      zB[base + t] = zr;
      zr += zseg[base + t];
    }
  }
}

// ------------- flash local attention + memory retrieval + gate -------------
// NOTE: attc may alias qb (in-place): each block reads only its own rows
// (staged to LDS before any write) within its own head's 128-col slice, and
// writes exactly that slice. Cross-block ranges are disjoint.
__global__ __launch_bounds__(256)
void attn_k(const u16* __restrict__ qb, const u16* __restrict__ kb, const u16* __restrict__ vb,
            const u16* __restrict__ memB, const float* __restrict__ zB,
            const float* __restrict__ betas, u16* __restrict__ attc)
{
  const int bid = blockIdx.x;   // b*512 + h*64 + seg*8 + rt
  const int rt = bid&7, seg=(bid>>3)&7, h=(bid>>6)&7, b=bid>>9;
  __shared__ __align__(16) float qs[64][132];
  __shared__ __align__(16) u16 kvs[2][64*136];
  __shared__ __align__(16) u16 pt[64*68];
  __shared__ __align__(16) float zs[128];
  const int t = threadIdx.x;
  const int ty = t>>4, tx = t&15;
  const size_t qkvbase = ((size_t)b*4096 + seg*512)*1024 + h*128;

  { // stage q tile (fp32)
    const int row = t>>2, c0 = (t&3)<<3;
    const size_t gr = qkvbase + (size_t)(rt*64 + row)*1024;
    #pragma unroll
    for (int i=0;i<4;i++){
      float f[8]; unpack8(*(const uint4*)(qb + gr + c0 + i*32), f);
      #pragma unroll
      for (int e=0;e<8;e++) qs[row][c0 + i*32 + e] = f[e];
    }
  }
  float m_run[4], l_run[4], acc[4][8];
  #pragma unroll
  for (int i=0;i<4;i++){
    m_run[i] = -__builtin_inff(); l_run[i]=0.f;
    #pragma unroll
    for (int c=0;c<8;c++) acc[i][c]=0.f;
  }
  const float scale = 0.08838834764831845f;

  for (int kc=0; kc<=rt; kc++){
    __syncthreads();
    { // stage k,v tiles (bf16)
      const int row = t>>2, c0 = (t&3)<<3;
      const size_t gr = qkvbase + (size_t)(kc*64 + row)*1024;
      #pragma unroll
      for (int i=0;i<4;i++){
        *(uint4*)&kvs[0][row*136 + c0 + i*32] = *(const uint4*)(kb + gr + c0 + i*32);
        *(uint4*)&kvs[1][row*136 + c0 + i*32] = *(const uint4*)(vb + gr + c0 + i*32);
      }
    }
    __syncthreads();
    float s[4][4];
    #pragma unroll
    for (int i=0;i<4;i++){ s[i][0]=0.f;s[i][1]=0.f;s[i][2]=0.f;s[i][3]=0.f; }
    for (int kd=0; kd<128; kd+=2){
      float2 q2[4];
      #pragma unroll
      for (int i=0;i<4;i++) q2[i] = *(const float2*)&qs[(ty<<2)+i][kd];
      #pragma unroll
      for (int j=0;j<4;j++){
        const u32 kk = *(const u32*)&kvs[0][((tx<<2)+j)*136 + kd];
        const float kx = b2f((u16)(kk&0xffffu)), ky = b2f((u16)(kk>>16));
        #pragma unroll
        for (int i=0;i<4;i++) s[i][j] += q2[i].x*kx + q2[i].y*ky;
      }
    }
    const bool diag = (kc==rt);
    float rm[4], p[4][4];
    #pragma unroll
    for (int i=0;i<4;i++){
      #pragma unroll
      for (int j=0;j<4;j++){
        float sv = s[i][j]*scale;
        if (diag && ((tx<<2)+j > (ty<<2)+i)) sv = -__builtin_inff();
        s[i][j]=sv;
      }
      rm[i] = fmaxf(fmaxf(s[i][0],s[i][1]), fmaxf(s[i][2],s[i][3]));
    }
    #pragma unroll
    for (int o=1;o<16;o<<=1)
      #pragma unroll
      for (int i=0;i<4;i++) rm[i] = fmaxf(rm[i], __shfl_xor(rm[i], o));
    float rs_[4];
    #pragma unroll
    for (int i=0;i<4;i++){
      const float mn = fmaxf(m_run[i], rm[i]);
      const float sc = expf(m_run[i] - mn);
      float rsum = 0.f;
      #pragma unroll
      for (int j=0;j<4;j++){ p[i][j] = expf(s[i][j]-mn); rsum += p[i][j]; }
      rs_[i] = rsum;
      m_run[i] = mn;
      l_run[i] *= sc;
      #pragma unroll
      for (int c=0;c<8;c++) acc[i][c] *= sc;
    }
    #pragma unroll
    for (int o=1;o<16;o<<=1)
      #pragma unroll
      for (int i=0;i<4;i++) rs_[i] += __shfl_xor(rs_[i], o);
    #pragma unroll
    for (int i=0;i<4;i++) l_run[i] += rs_[i];
    // p -> LDS (rows owned by this thread's wave; same-wave ordering)
    #pragma unroll
    for (int i=0;i<4;i++){
      uint2 pw; pw.x = pack2(p[i][0],p[i][1]); pw.y = pack2(p[i][2],p[i][3]);
      *(uint2*)&pt[((ty<<2)+i)*68 + (tx<<2)] = pw;
    }
    // PV
    for (int j=0;j<64;j++){
      float vf[8]; unpack8(*(const uint4*)&kvs[1][j*136 + (tx<<3)], vf);
      float pv[4];
      #pragma unroll
      for (int i=0;i<4;i++) pv[i] = b2f(pt[((ty<<2)+i)*68 + j]);
      #pragma unroll
      for (int i=0;i<4;i++)
        #pragma unroll
        for (int c=0;c<8;c++) acc[i][c] += pv[i]*vf[c];
    }
  }
  // ---- epilogue: compressive-memory retrieval + gated combine ----
  __syncthreads();
  {
    u16* mb = &kvs[0][0];
    const size_t mbase = (((size_t)b*8 + h)*8 + seg)*16384;
    #pragma unroll
    for (int i=0;i<8;i++){
      const int idx = t + (i<<8);
      *(uint4*)&mb[idx<<3] = *(const uint4*)(memB + mbase + ((size_t)idx<<3));
    }
    if (t < 128) zs[t] = zB[(((size_t)b*8+h)*8+seg)*128 + t];
  }
  __syncthreads();
  float num[4][8], den[4];
  #pragma unroll
  for (int i=0;i<4;i++){ den[i]=0.f;
    #pragma unroll
    for (int c=0;c<8;c++) num[i][c]=0.f; }
  const u16* mb = &kvs[0][0];
  for (int kd=0; kd<128; kd++){
    float sq[4];
    #pragma unroll
    for (int i=0;i<4;i++){
      const float qv = qs[(ty<<2)+i][kd];
      sq[i] = qv>0.f ? qv+1.f : expf(qv);   // elu(q)+1
    }
    const float zv = zs[kd];
    float mv[8]; unpack8(*(const uint4*)&mb[(kd<<7) + (tx<<3)], mv);
    #pragma unroll
    for (int i=0;i<4;i++){
      den[i] += sq[i]*zv;
      #pragma unroll
      for (int c=0;c<8;c++) num[i][c] += sq[i]*mv[c];
    }
  }
  float gate[8];
  #pragma unroll
  for (int c=0;c<8;c++){
    const float bv = betas[(h<<7) + (tx<<3) + c];
    gate[c] = 1.f/(1.f + expf(-bv));
  }
  #pragma unroll
  for (int i=0;i<4;i++){
    const float linv = 1.f/l_run[i];
    const float dinv = 1.f/den[i];
    float o[8];
    #pragma unroll
    for (int c=0;c<8;c++){
      const float att = acc[i][c]*linv;
      const float am  = num[i][c]*dinv;
      o[c] = gate[c]*am + (1.f-gate[c])*att;
    }
    u16* op = attc + qkvbase + (size_t)(rt*64 + (ty<<2)+i)*1024 + (tx<<3);
    *(uint4*)op = pack8(o);
  }
}

extern "C" void kernel_launch(void* const* d_in, const int* in_sizes, int n_in,
                              void* d_out, int out_size, void* d_ws, size_t ws_size,
                              hipStream_t stream)
{
  (void)in_sizes; (void)n_in; (void)out_size; (void)ws_size;
  const float* x    = (const float*)d_in[0];
  const float* ln_g = (const float*)d_in[1];
  const float* ln_b = (const float*)d_in[2];
  const float* Wq   = (const float*)d_in[3];
  const float* Wk   = (const float*)d_in[4];
  const float* Wv   = (const float*)d_in[5];
  const float* Wo   = (const float*)d_in[6];
  const float* betas= (const float*)d_in[7];
  const float* w1   = (const float*)d_in[8];
  const float* b1   = (const float*)d_in[9];
  const float* w2   = (const float*)d_in[10];
  const float* b2   = (const float*)d_in[11];
  float* out = (float*)d_out;

  // ---- 128 MiB workspace: 4 x 32 MiB buffers with stream-ordered reuse ----
  char* ws = (char*)d_ws;
  const size_t MB32 = 33554432;
  u16* bufA = (u16*)(ws);               // h  -> {Mseg, memB, zseg, zB}
  u16* bufB = (u16*)(ws + MB32);        // qb -> at (in-place)
  u16* bufC = (u16*)(ws + 2*MB32);      // kb -> h2
  u16* bufD = (u16*)(ws + 3*MB32);      // vb -> gb (FF hidden, 4 chunks)

  u16*   h    = bufA;
  u16*   qb   = bufB;
  u16*   kb   = bufC;
  u16*   vb   = bufD;
  float* Mseg = (float*)(ws);                     // 16 MiB (after h is dead)
  u16*   memB = (u16*)(ws + 16777216);            // 8 MiB
  float* zseg = (float*)(ws + 25165824);          // 128 KiB
  float* zB   = (float*)(ws + 25296896);          // 128 KiB
  u16*   at   = bufB;                             // in-place over qb
  u16*   h2   = bufC;                             // over kb
  u16*   gb   = bufD;                             // over vb, 32 MiB per chunk

  ln_k<<<16384,256,0,stream>>>(x, ln_g, ln_b, h);
  dim3 g1(8,128);
  gemm_k<EPI_BF16><<<g1,256,0,stream>>>(h, Wq, 1024,1024, qb, nullptr, nullptr, nullptr);
  gemm_k<EPI_BF16><<<g1,256,0,stream>>>(h, Wk, 1024,1024, kb, nullptr, nullptr, nullptr);
  gemm_k<EPI_BF16><<<g1,256,0,stream>>>(h, Wv, 1024,1024, vb, nullptr, nullptr, nullptr);
  memseg_k<<<256,256,0,stream>>>(kb, vb, Mseg, zseg);      // overwrites h region
  scan_k<<<32,256,0,stream>>>(Mseg, zseg, memB, zB);
  attn_k<<<2048,256,0,stream>>>(qb, kb, vb, memB, zB, betas, at);
  gemm_k<EPI_WO><<<g1,256,0,stream>>>(at, Wo, 1024,1024, nullptr, out, x, nullptr);
  ln_k<<<16384,256,0,stream>>>(out, ln_g, ln_b, h2);
  // FF chunked over rows: 4 chunks of 4096 rows (hidden chunk = 32 MiB bf16)
  for (int c = 0; c < 4; c++){
    const u16*  hA = h2 + (size_t)c*4096*1024;
    float*      oC = out + (size_t)c*4096*1024;
    dim3 gf1(32,32), gf2(8,32);
    gemm_k<EPI_GELU><<<gf1,256,0,stream>>>(hA, w1, 1024,4096, gb, nullptr, nullptr, b1);
    gemm_k<EPI_FF2><<<gf2,256,0,stream>>>(gb, w2, 4096,1024, nullptr, oC, nullptr, b2);
  }
}

// Round 3
// 1785.716 us; speedup vs baseline: 1.3897x; 1.3897x over previous
//
#include <hip/hip_runtime.h>

typedef unsigned short u16;
typedef unsigned int   u32;
typedef float f32x4 __attribute__((ext_vector_type(4)));
typedef short bf16x8 __attribute__((ext_vector_type(8)));

#define DEV static __device__ __forceinline__

DEV u16 f2b(float f){
  u32 u = __builtin_bit_cast(u32, f);
  return (u16)((u + 0x7fffu + ((u >> 16) & 1u)) >> 16);
}
DEV float b2f(u16 h){ u32 u = ((u32)h) << 16; return __builtin_bit_cast(float, u); }
DEV u32 pack2(float a, float b){ return (u32)f2b(a) | ((u32)f2b(b) << 16); }
DEV uint4 pack8(const float* f){
  uint4 r; r.x = pack2(f[0],f[1]); r.y = pack2(f[2],f[3]);
  r.z = pack2(f[4],f[5]); r.w = pack2(f[6],f[7]); return r;
}
DEV void unpack8(uint4 u, float* f){
  f[0]=b2f((u16)(u.x&0xffffu)); f[1]=b2f((u16)(u.x>>16));
  f[2]=b2f((u16)(u.y&0xffffu)); f[3]=b2f((u16)(u.y>>16));
  f[4]=b2f((u16)(u.z&0xffffu)); f[5]=b2f((u16)(u.z>>16));
  f[6]=b2f((u16)(u.w&0xffffu)); f[7]=b2f((u16)(u.w>>16));
}
DEV float gelu_t(float x){
  return 0.5f*x*(1.f + tanhf(0.7978845608028654f*(x + 0.044715f*x*x*x)));
}

// ---------------- LayerNorm: fp32 [rows][1024] -> bf16 ----------------
__global__ __launch_bounds__(256)
void ln_k(const float* __restrict__ x, const float* __restrict__ gamma,
          const float* __restrict__ beta, u16* __restrict__ out)
{
  const int row = blockIdx.x;
  const int t = threadIdx.x;
  const float4 v = ((const float4*)(x + (size_t)row*1024))[t];
  float s  = v.x+v.y+v.z+v.w;
  float ss = v.x*v.x+v.y*v.y+v.z*v.z+v.w*v.w;
  #pragma unroll
  for (int o=32;o;o>>=1){ s += __shfl_xor(s,o); ss += __shfl_xor(ss,o); }
  __shared__ float rs[4], rq[4];
  if ((t&63)==0){ rs[t>>6]=s; rq[t>>6]=ss; }
  __syncthreads();
  s  = rs[0]+rs[1]+rs[2]+rs[3];
  ss = rq[0]+rq[1]+rq[2]+rq[3];
  const float mean = s*(1.f/1024.f);
  const float var  = ss*(1.f/1024.f) - mean*mean;
  const float inv  = rsqrtf(var + 1e-5f);
  const float4 g4 = ((const float4*)gamma)[t];
  const float4 b4 = ((const float4*)beta)[t];
  float o[4];
  o[0]=(v.x-mean)*inv*g4.x+b4.x; o[1]=(v.y-mean)*inv*g4.y+b4.y;
  o[2]=(v.z-mean)*inv*g4.z+b4.z; o[3]=(v.w-mean)*inv*g4.w+b4.w;
  uint2 w; w.x = pack2(o[0],o[1]); w.y = pack2(o[2],o[3]);
  *(uint2*)(out + (size_t)row*1024 + t*4) = w;
}

// ---------------- bf16 MFMA GEMM, 128x128 tile, BK=32 ----------------
#define EPI_BF16 0
#define EPI_WO   1
#define EPI_GELU 2
#define EPI_FF2  3

template<int EPI>
__global__ __launch_bounds__(256)
void gemm_k(const u16* __restrict__ A, const float* __restrict__ B,
            int K, int N, u16* __restrict__ obf, float* __restrict__ of32,
            const float* __restrict__ res, const float* __restrict__ bias)
{
  __shared__ __align__(16) u16 As[128][40];   // [m][k], pad
  __shared__ __align__(16) u16 Bs[128][40];   // B^T: [n][k]
  const int t = threadIdx.x;
  const int m0 = blockIdx.y << 7, n0 = blockIdx.x << 7;
  const int wave = t >> 6, lane = t & 63;
  const int wm = (wave >> 1) << 6, wn = (wave & 1) << 6;
  const int r16 = lane & 15, g = lane >> 4;
  const int arow = t >> 1, ak = (t & 1) << 4;
  const int bn = (t & 63) << 1, bk = (t >> 6) << 3;

  f32x4 acc[4][4];
  const f32x4 zz = {0.f,0.f,0.f,0.f};
  #pragma unroll
  for (int i=0;i<4;i++) { acc[i][0]=zz; acc[i][1]=zz; acc[i][2]=zz; acc[i][3]=zz; }

  for (int k0 = 0; k0 < K; k0 += 32){
    const uint4* ap = (const uint4*)(A + (size_t)(m0+arow)*K + k0 + ak);
    const uint4 a0 = ap[0], a1 = ap[1];
    const float* bp = B + (size_t)(k0+bk)*N + n0 + bn;
    float e0[8], e1[8];
    #pragma unroll
    for (int i=0;i<8;i++){
      const float2 f = *(const float2*)(bp + (size_t)i*N);
      e0[i]=f.x; e1[i]=f.y;
    }
    __syncthreads();
    *(uint4*)&As[arow][ak]   = a0;
    *(uint4*)&As[arow][ak+8] = a1;
    *(uint4*)&Bs[bn][bk]     = pack8(e0);
    *(uint4*)&Bs[bn+1][bk]   = pack8(e1);
    __syncthreads();
    bf16x8 af[4], bfv[4];
    #pragma unroll
    for (int i=0;i<4;i++) af[i]  = *(const bf16x8*)&As[wm + (i<<4) + r16][g<<3];
    #pragma unroll
    for (int j=0;j<4;j++) bfv[j] = *(const bf16x8*)&Bs[wn + (j<<4) + r16][g<<3];
    #pragma unroll
    for (int i=0;i<4;i++)
      #pragma unroll
      for (int j=0;j<4;j++)
        acc[i][j] = __builtin_amdgcn_mfma_f32_16x16x32_bf16(af[i], bfv[j], acc[i][j], 0,0,0);
  }

  #pragma unroll
  for (int i=0;i<4;i++){
    #pragma unroll
    for (int j=0;j<4;j++){
      const int gc = n0 + wn + (j<<4) + r16;
      #pragma unroll
      for (int r=0;r<4;r++){
        const int gr = m0 + wm + (i<<4) + (g<<2) + r;
        const size_t idx = (size_t)gr*N + gc;
        const float vv = acc[i][j][r];
        if (EPI==EPI_BF16)      obf[idx] = f2b(vv);
        else if (EPI==EPI_WO)   of32[idx] = res[idx] + vv;
        else if (EPI==EPI_GELU) obf[idx] = f2b(gelu_t(vv + bias[gc]));
        else                    of32[idx] = of32[idx] + vv + bias[gc];
      }
    }
  }
}

// ------------- per-segment memory contribution: Mseg, zseg -------------
__global__ __launch_bounds__(256)
void memseg_k(const u16* __restrict__ kb, const u16* __restrict__ vb,
              float* __restrict__ Mseg, float* __restrict__ zseg)
{
  const int bid = blockIdx.x;           // b*64 + h*8 + seg
  const int seg = bid & 7, h = (bid>>3)&7, b = bid>>6;
  __shared__ __align__(16) u16 ks[64][136];
  __shared__ __align__(16) u16 vs[64][136];
  const int t = threadIdx.x;
  const int srow = t>>2, sc = (t&3)<<3;
  const int ty = t>>4, tx = t&15;
  float acc[8][8];
  #pragma unroll
  for (int i=0;i<8;i++)
    #pragma unroll
    for (int j=0;j<8;j++) acc[i][j]=0.f;
  float zacc = 0.f;

  for (int s0=0; s0<512; s0+=64){
    __syncthreads();
    const size_t gr = ((size_t)b*4096 + seg*512 + s0 + srow)*1024 + h*128;
    #pragma unroll
    for (int i=0;i<4;i++){
      float f[8]; unpack8(*(const uint4*)(kb + gr + sc + i*32), f);
      #pragma unroll
      for (int e=0;e<8;e++) f[e] = f[e]>0.f ? f[e]+1.f : __expf(f[e]); // elu+1
      *(uint4*)&ks[srow][sc + i*32] = pack8(f);
      *(uint4*)&vs[srow][sc + i*32] = *(const uint4*)(vb + gr + sc + i*32);
    }
    __syncthreads();
    for (int s=0;s<64;s++){
      float kf[8], vf[8];
      unpack8(*(const uint4*)&ks[s][ty<<3], kf);
      unpack8(*(const uint4*)&vs[s][tx<<3], vf);
      #pragma unroll
      for (int i=0;i<8;i++)
        #pragma unroll
        for (int j=0;j<8;j++) acc[i][j] += kf[i]*vf[j];
    }
    if (t < 128){
      for (int s=0;s<64;s++) zacc += b2f(ks[s][t]);
    }
  }
  const size_t mb = (size_t)bid*16384;
  #pragma unroll
  for (int i=0;i<8;i++)
    #pragma unroll
    for (int j=0;j<8;j++)
      Mseg[mb + (size_t)((ty<<3)+i)*128 + (tx<<3)+j] = acc[i][j];
  if (t < 128) zseg[(size_t)bid*128 + t] = zacc;
}

// --- prefix scan over segments -> memBT (TRANSPOSED [dv][kd], bf16), zB ---
__global__ __launch_bounds__(256)
void scan_k(const float* __restrict__ Mseg, const float* __restrict__ zseg,
            u16* __restrict__ memBT, float* __restrict__ zB)
{
  const int bh = blockIdx.x;   // b*8+h
  const int t = threadIdx.x;
  float run[64];
  #pragma unroll
  for (int i=0;i<64;i++) run[i]=0.f;
  for (int seg=0; seg<8; seg++){
    const size_t base = ((size_t)bh*8 + seg)*16384;
    #pragma unroll
    for (int i=0;i<64;i++){
      const int n = t + (i<<8);          // = kd*128 + dv
      const int kd = n >> 7, dv = n & 127;
      memBT[base + (size_t)dv*128 + kd] = f2b(run[i]);
    }
    #pragma unroll
    for (int i=0;i<64;i++) run[i] += Mseg[base + t + (i<<8)];
  }
  if (t < 128){
    float zr = 1.f/128.f;
    for (int seg=0; seg<8; seg++){
      const size_t base = ((size_t)bh*8 + seg)*128;
      zB[base + t] = zr;
      zr += zseg[base + t];
    }
  }
}

// ------- compressive-memory retrieval (MFMA): rmem = gate * (sq@mem)/(sq@z) -------
// Runs BEFORE attn_k (reads raw q). Writes bf16 into rmem (d_out scratch).
__global__ __launch_bounds__(256)
void retr_k(const u16* __restrict__ qb, const u16* __restrict__ memBT,
            const float* __restrict__ zB, const float* __restrict__ betas,
            u16* __restrict__ rmem)
{
  const int bid = blockIdx.x;            // b*128 + h*16 + seg*2 + half
  const int half = bid&1, seg=(bid>>1)&7, h=(bid>>4)&7, b=bid>>7;
  __shared__ __align__(16) u16 memT[128][136];
  __shared__ float zsl[128];
  const int t=threadIdx.x, w=t>>6, lane=t&63, c=lane&15, g=lane>>4;
  const size_t mbase = (((size_t)b*8+h)*8+seg)*16384;
  #pragma unroll
  for (int i=0;i<8;i++){
    const int n8 = t + (i<<8);           // 8-elem chunk index over [dv][kd]
    *(uint4*)&memT[n8>>4][(n8&15)<<3] = *(const uint4*)(memBT + mbase + ((size_t)n8<<3));
  }
  if (t<128) zsl[t] = zB[(((size_t)b*8+h)*8+seg)*128 + t];
  __syncthreads();

  bf16x8 bz[4];
  #pragma unroll
  for (int ks=0;ks<4;ks++){
    uint4 zr = {0,0,0,0};
    if (c==0) zr = pack8(&zsl[ks*32 + g*8]);
    bz[ks] = __builtin_bit_cast(bf16x8, zr);
  }
  const size_t base = ((size_t)b*4096 + seg*512)*1024 + h*128;
  const int q0 = half*256 + w*64;
  for (int qt=0; qt<4; qt++){
    const int q16 = q0 + qt*16;
    bf16x8 af[4];
    #pragma unroll
    for (int ks=0;ks<4;ks++){
      const uint4 raw = *(const uint4*)(qb + base + (size_t)(q16 + c)*1024 + ks*32 + g*8);
      float f[8]; unpack8(raw, f);
      #pragma unroll
      for (int e=0;e<8;e++) f[e] = f[e]>0.f ? f[e]+1.f : __expf(f[e]);  // elu+1
      af[ks] = __builtin_bit_cast(bf16x8, pack8(f));
    }
    f32x4 nacc[8];
    f32x4 zacc = {0.f,0.f,0.f,0.f};
    #pragma unroll
    for (int f=0;f<8;f++) nacc[f] = zacc;
    #pragma unroll
    for (int ks=0;ks<4;ks++){
      zacc = __builtin_amdgcn_mfma_f32_16x16x32_bf16(af[ks], bz[ks], zacc, 0,0,0);
      #pragma unroll
      for (int f=0;f<8;f++){
        const bf16x8 bm = *(const bf16x8*)&memT[f*16 + c][ks*32 + g*8];
        nacc[f] = __builtin_amdgcn_mfma_f32_16x16x32_bf16(af[ks], bm, nacc[f], 0,0,0);
      }
    }
    float den[4];
    #pragma unroll
    for (int r=0;r<4;r++) den[r] = 1.f / __shfl(zacc[r], lane & 48);
    #pragma unroll
    for (int f=0;f<8;f++){
      const float bv = betas[h*128 + f*16 + c];
      const float gate = 1.f/(1.f+__expf(-bv));
      #pragma unroll
      for (int r=0;r<4;r++){
        const float am = nacc[f][r] * den[r];
        rmem[base + (size_t)(q16 + g*4 + r)*1024 + f*16 + c] = f2b(gate*am);
      }
    }
  }
}

// ------------- flash local attention (MFMA) + combine with rmem -------------
// In-place: attc == qb (each block reads only its own q rows, staged before write).
__global__ __launch_bounds__(256)
void attn_k(const u16* __restrict__ qb, const u16* __restrict__ kb,
            const u16* __restrict__ vb, const u16* __restrict__ rmem,
            const float* __restrict__ betas, u16* __restrict__ attc)
{
  const int bid = blockIdx.x;   // b*512 + h*64 + seg*8 + rt
  const int rt = bid&7, seg=(bid>>3)&7, h=(bid>>6)&7, b=bid>>9;
  __shared__ __align__(16) u16 QPs[64][136];  // Q tile, then reused as P tile
  __shared__ __align__(16) u16 Ks[64][136];
  __shared__ __align__(16) u16 Vt[128][72];   // V transposed [dv][kr]
  const int t=threadIdx.x, w=t>>6, lane=t&63, c=lane&15, g=lane>>4;
  const size_t base = ((size_t)b*4096 + seg*512)*1024 + h*128;

  { // Q stage (wave-local rows: wave w stages rows 16w..16w+15)
    const int row = t>>2, c0 = (t&3)<<5;
    const u16* src = qb + base + (size_t)(rt*64+row)*1024 + c0;
    #pragma unroll
    for (int jj=0;jj<4;jj++)
      *(uint4*)&QPs[row][c0 + jj*8] = *(const uint4*)(src + jj*8);
  }
  bf16x8 af[4];
  #pragma unroll
  for (int ks=0;ks<4;ks++) af[ks] = *(const bf16x8*)&QPs[w*16 + c][ks*32 + g*8];

  f32x4 acc[8];
  #pragma unroll
  for (int f=0;f<8;f++) acc[f] = (f32x4){0.f,0.f,0.f,0.f};
  float m_run[4], l_run[4];
  #pragma unroll
  for (int r=0;r<4;r++){ m_run[r] = -1e30f; l_run[r] = 0.f; }
  const float scl = 0.08838834764831845f;

  for (int kc=0; kc<=rt; kc++){
    __syncthreads();
    { // stage K rows; stage V transposed (wave w stages dv cols 32w..32w+31)
      const int row = t>>2, c0 = (t&3)<<5;
      const u16* ksrc = kb + base + (size_t)(kc*64+row)*1024 + c0;
      #pragma unroll
      for (int jj=0;jj<4;jj++)
        *(uint4*)&Ks[row][c0 + jj*8] = *(const uint4*)(ksrc + jj*8);
      const int kr = t & 63, d0 = (t>>6)<<5;
      const u16* vsrc = vb + base + (size_t)(kc*64+kr)*1024 + d0;
      #pragma unroll
      for (int jj=0;jj<4;jj++){
        const uint4 vv = *(const uint4*)(vsrc + jj*8);
        u16 tmp[8]; *(uint4*)tmp = vv;
        #pragma unroll
        for (int e=0;e<8;e++) Vt[d0 + jj*8 + e][kr] = tmp[e];
      }
    }
    __syncthreads();
    // QK^T: S[16q x 64kr] per wave
    f32x4 s[4];
    #pragma unroll
    for (int j=0;j<4;j++) s[j] = (f32x4){0.f,0.f,0.f,0.f};
    #pragma unroll
    for (int ks=0;ks<4;ks++)
      #pragma unroll
      for (int j=0;j<4;j++){
        const bf16x8 bk = *(const bf16x8*)&Ks[j*16 + c][ks*32 + g*8];
        s[j] = __builtin_amdgcn_mfma_f32_16x16x32_bf16(af[ks], bk, s[j], 0,0,0);
      }
    const bool diag = (kc==rt);
    float p[4][4], rm[4], rs[4];
    #pragma unroll
    for (int r=0;r<4;r++){
      float mx = -1e30f;
      #pragma unroll
      for (int j=0;j<4;j++){
        float sv = s[j][r]*scl;
        if (diag && (j*16+c) > (w*16 + g*4 + r)) sv = -1e30f;
        p[j][r] = sv;
        mx = fmaxf(mx, sv);
      }
      rm[r] = mx;
    }
    #pragma unroll
    for (int o=1;o<16;o<<=1)
      #pragma unroll
      for (int r=0;r<4;r++) rm[r] = fmaxf(rm[r], __shfl_xor(rm[r], o));
    #pragma unroll
    for (int r=0;r<4;r++){
      const float mn = fmaxf(m_run[r], rm[r]);
      const float sc = __expf(m_run[r] - mn);
      m_run[r] = mn;
      float sum = 0.f;
      #pragma unroll
      for (int j=0;j<4;j++){ p[j][r] = __expf(p[j][r]-mn); sum += p[j][r]; }
      rs[r] = sum;
      l_run[r] *= sc;
      #pragma unroll
      for (int f=0;f<8;f++) acc[f][r] *= sc;
    }
    #pragma unroll
    for (int o=1;o<16;o<<=1)
      #pragma unroll
      for (int r=0;r<4;r++) rs[r] += __shfl_xor(rs[r], o);
    #pragma unroll
    for (int r=0;r<4;r++) l_run[r] += rs[r];
    // P -> LDS (wave-local rows of QPs; cols 0..63)
    #pragma unroll
    for (int j=0;j<4;j++)
      #pragma unroll
      for (int r=0;r<4;r++)
        QPs[w*16 + g*4 + r][j*16 + c] = f2b(p[j][r]);
    // PV
    #pragma unroll
    for (int ks2=0; ks2<2; ks2++){
      const bf16x8 pa = *(const bf16x8*)&QPs[w*16 + c][ks2*32 + g*8];
      #pragma unroll
      for (int f=0;f<8;f++){
        const bf16x8 bv = *(const bf16x8*)&Vt[f*16 + c][ks2*32 + g*8];
        acc[f] = __builtin_amdgcn_mfma_f32_16x16x32_bf16(pa, bv, acc[f], 0,0,0);
      }
    }
  }
  // epilogue: out = rmem + (1-gate)*att
  #pragma unroll
  for (int f=0;f<8;f++){
    const float bv = betas[h*128 + f*16 + c];
    const float gate = 1.f/(1.f+__expf(-bv));
    #pragma unroll
    for (int r=0;r<4;r++){
      const size_t idx = base + (size_t)(rt*64 + w*16 + g*4 + r)*1024 + f*16 + c;
      const float att = acc[f][r] / l_run[r];
      attc[idx] = f2b(b2f(rmem[idx]) + (1.f-gate)*att);
    }
  }
}

extern "C" void kernel_launch(void* const* d_in, const int* in_sizes, int n_in,
                              void* d_out, int out_size, void* d_ws, size_t ws_size,
                              hipStream_t stream)
{
  (void)in_sizes; (void)n_in; (void)out_size; (void)ws_size;
  const float* x    = (const float*)d_in[0];
  const float* ln_g = (const float*)d_in[1];
  const float* ln_b = (const float*)d_in[2];
  const float* Wq   = (const float*)d_in[3];
  const float* Wk   = (const float*)d_in[4];
  const float* Wv   = (const float*)d_in[5];
  const float* Wo   = (const float*)d_in[6];
  const float* betas= (const float*)d_in[7];
  const float* w1   = (const float*)d_in[8];
  const float* b1   = (const float*)d_in[9];
  const float* w2   = (const float*)d_in[10];
  const float* b2   = (const float*)d_in[11];
  float* out = (float*)d_out;

  // ---- 128 MiB workspace: 4 x 32 MiB buffers with stream-ordered reuse ----
  char* ws = (char*)d_ws;
  const size_t MB32 = 33554432;
  u16*   h    = (u16*)(ws);                       // bufA
  u16*   qb   = (u16*)(ws + MB32);                // bufB: qb -> at (in-place)
  u16*   kb   = (u16*)(ws + 2*MB32);              // bufC: kb -> h2
  u16*   vb   = (u16*)(ws + 3*MB32);              // bufD: vb -> gb
  float* Mseg = (float*)(ws);                     // 16 MiB (after h dead)
  u16*   memBT= (u16*)(ws + 16777216);            // 8 MiB, [dv][kd]
  float* zseg = (float*)(ws + 25165824);          // 128 KiB
  float* zB   = (float*)(ws + 25296896);          // 128 KiB
  u16*   at   = qb;                               // in-place
  u16*   h2   = kb;
  u16*   gb   = vb;
  u16*   rmem = (u16*)out;                        // d_out as bf16 scratch (dead until Wo)

  ln_k<<<16384,256,0,stream>>>(x, ln_g, ln_b, h);
  dim3 g1(8,128);
  gemm_k<EPI_BF16><<<g1,256,0,stream>>>(h, Wq, 1024,1024, qb, nullptr, nullptr, nullptr);
  gemm_k<EPI_BF16><<<g1,256,0,stream>>>(h, Wk, 1024,1024, kb, nullptr, nullptr, nullptr);
  gemm_k<EPI_BF16><<<g1,256,0,stream>>>(h, Wv, 1024,1024, vb, nullptr, nullptr, nullptr);
  memseg_k<<<256,256,0,stream>>>(kb, vb, Mseg, zseg);
  scan_k<<<32,256,0,stream>>>(Mseg, zseg, memBT, zB);
  retr_k<<<512,256,0,stream>>>(qb, memBT, zB, betas, rmem);
  attn_k<<<2048,256,0,stream>>>(qb, kb, vb, rmem, betas, at);
  gemm_k<EPI_WO><<<g1,256,0,stream>>>(at, Wo, 1024,1024, nullptr, out, x, nullptr);
  ln_k<<<16384,256,0,stream>>>(out, ln_g, ln_b, h2);
  // FF chunked over rows: 4 chunks of 4096 rows (hidden chunk = 32 MiB bf16)
  for (int c = 0; c < 4; c++){
    const u16*  hA = h2 + (size_t)c*4096*1024;
    float*      oC = out + (size_t)c*4096*1024;
    dim3 gf1(32,32), gf2(8,32);
    gemm_k<EPI_GELU><<<gf1,256,0,stream>>>(hA, w1, 1024,4096, gb, nullptr, nullptr, b1);
    gemm_k<EPI_FF2><<<gf2,256,0,stream>>>(gb, w2, 4096,1024, nullptr, oC, nullptr, b2);
  }
}

// Round 4
// 1327.470 us; speedup vs baseline: 1.8695x; 1.3452x over previous
//
#include <hip/hip_runtime.h>

typedef unsigned short u16;
typedef unsigned int   u32;
typedef float f32x4 __attribute__((ext_vector_type(4)));
typedef short bf16x8 __attribute__((ext_vector_type(8)));

#define DEV static __device__ __forceinline__

DEV u16 f2b(float f){
  u32 u = __builtin_bit_cast(u32, f);
  return (u16)((u + 0x7fffu + ((u >> 16) & 1u)) >> 16);
}
DEV float b2f(u16 h){ u32 u = ((u32)h) << 16; return __builtin_bit_cast(float, u); }
DEV u32 pack2(float a, float b){ return (u32)f2b(a) | ((u32)f2b(b) << 16); }
DEV uint4 pack8(const float* f){
  uint4 r; r.x = pack2(f[0],f[1]); r.y = pack2(f[2],f[3]);
  r.z = pack2(f[4],f[5]); r.w = pack2(f[6],f[7]); return r;
}
DEV void unpack8(uint4 u, float* f){
  f[0]=b2f((u16)(u.x&0xffffu)); f[1]=b2f((u16)(u.x>>16));
  f[2]=b2f((u16)(u.y&0xffffu)); f[3]=b2f((u16)(u.y>>16));
  f[4]=b2f((u16)(u.z&0xffffu)); f[5]=b2f((u16)(u.z>>16));
  f[6]=b2f((u16)(u.w&0xffffu)); f[7]=b2f((u16)(u.w>>16));
}
DEV float gelu_t(float x){
  return 0.5f*x*(1.f + tanhf(0.7978845608028654f*(x + 0.044715f*x*x*x)));
}
// async global->LDS, 16B per lane; LDS dest = wave-uniform base + lane*16
DEV void g2l16(const u16* g, u16* l){
  __builtin_amdgcn_global_load_lds(
    (const __attribute__((address_space(1))) u32*)g,
    (__attribute__((address_space(3))) u32*)l, 16, 0, 0);
}

// ---------------- LayerNorm: fp32 [rows][1024] -> bf16 ----------------
__global__ __launch_bounds__(256)
void ln_k(const float* __restrict__ x, const float* __restrict__ gamma,
          const float* __restrict__ beta, u16* __restrict__ out)
{
  const int row = blockIdx.x;
  const int t = threadIdx.x;
  const float4 v = ((const float4*)(x + (size_t)row*1024))[t];
  float s  = v.x+v.y+v.z+v.w;
  float ss = v.x*v.x+v.y*v.y+v.z*v.z+v.w*v.w;
  #pragma unroll
  for (int o=32;o;o>>=1){ s += __shfl_xor(s,o); ss += __shfl_xor(ss,o); }
  __shared__ float rs[4], rq[4];
  if ((t&63)==0){ rs[t>>6]=s; rq[t>>6]=ss; }
  __syncthreads();
  s  = rs[0]+rs[1]+rs[2]+rs[3];
  ss = rq[0]+rq[1]+rq[2]+rq[3];
  const float mean = s*(1.f/1024.f);
  const float var  = ss*(1.f/1024.f) - mean*mean;
  const float inv  = rsqrtf(var + 1e-5f);
  const float4 g4 = ((const float4*)gamma)[t];
  const float4 b4 = ((const float4*)beta)[t];
  float o[4];
  o[0]=(v.x-mean)*inv*g4.x+b4.x; o[1]=(v.y-mean)*inv*g4.y+b4.y;
  o[2]=(v.z-mean)*inv*g4.z+b4.z; o[3]=(v.w-mean)*inv*g4.w+b4.w;
  uint2 w; w.x = pack2(o[0],o[1]); w.y = pack2(o[2],o[3]);
  *(uint2*)(out + (size_t)row*1024 + t*4) = w;
}

// ------------- weight conversion: W [K][N] fp32 -> WT [N][K] bf16 -------------
__global__ __launch_bounds__(256)
void wconv_k(const float* __restrict__ W, u16* __restrict__ WT, int K, int N)
{
  __shared__ float tile[32][33];
  const int k0 = blockIdx.y<<5, n0 = blockIdx.x<<5;
  const int tx = threadIdx.x & 31, ty = threadIdx.x >> 5;   // 32 x 8
  #pragma unroll
  for (int r=0;r<32;r+=8)
    tile[ty+r][tx] = W[(size_t)(k0+ty+r)*N + n0+tx];
  __syncthreads();
  #pragma unroll
  for (int r=0;r<32;r+=8)
    WT[(size_t)(n0+ty+r)*K + k0+tx] = f2b(tile[tx][ty+r]);
}

// ------- bf16 MFMA GEMM, 128x128 tile, BK=32, global_load_lds staging -------
// A [M][K] bf16 row-major; BT [N][K] bf16 row-major (both K-contiguous).
#define EPI_BF16 0
#define EPI_WO   1
#define EPI_GELU 2
#define EPI_FF2  3

template<int EPI>
__global__ __launch_bounds__(256)
void gemm2_k(const u16* __restrict__ A, const u16* __restrict__ BT,
             int K, int N, u16* __restrict__ obf, float* __restrict__ of32,
             const float* __restrict__ res, const float* __restrict__ bias)
{
  __shared__ __align__(16) u16 As[128*32];   // linear [row][32] (64B rows)
  __shared__ __align__(16) u16 Bs[128*32];
  const int t = threadIdx.x, w = t>>6, lane = t&63;
  const int m0 = blockIdx.y<<7, n0 = blockIdx.x<<7;
  const int wm = (w>>1)<<6, wn = (w&1)<<6;
  const int c = lane&15, g = lane>>4;
  // staging: wave w, load l covers rows (w*2+l)*16 + lane/4, k-elems (lane&3)*8
  const u16* aSrc = A  + (size_t)(m0 + (w<<5) + (lane>>2))*K + ((lane&3)<<3);
  const u16* bSrc = BT + (size_t)(n0 + (w<<5) + (lane>>2))*K + ((lane&3)<<3);
  u16* aDst0 = &As[(w<<10)];          // (w*2+0)*512
  u16* aDst1 = &As[(w<<10) + 512];
  u16* bDst0 = &Bs[(w<<10)];
  u16* bDst1 = &Bs[(w<<10) + 512];

  f32x4 acc[4][4];
  const f32x4 zz = {0.f,0.f,0.f,0.f};
  #pragma unroll
  for (int i=0;i<4;i++){ acc[i][0]=zz; acc[i][1]=zz; acc[i][2]=zz; acc[i][3]=zz; }

  for (int k0 = 0; k0 < K; k0 += 32){
    __syncthreads();
    g2l16(aSrc + k0,               aDst0);
    g2l16(aSrc + k0 + (size_t)16*K, aDst1);
    g2l16(bSrc + k0,               bDst0);
    g2l16(bSrc + k0 + (size_t)16*K, bDst1);
    __syncthreads();
    bf16x8 af[4], bf[4];
    #pragma unroll
    for (int i=0;i<4;i++) af[i] = *(const bf16x8*)&As[(wm + (i<<4) + c)*32 + (g<<3)];
    #pragma unroll
    for (int j=0;j<4;j++) bf[j] = *(const bf16x8*)&Bs[(wn + (j<<4) + c)*32 + (g<<3)];
    #pragma unroll
    for (int i=0;i<4;i++)
      #pragma unroll
      for (int j=0;j<4;j++)
        acc[i][j] = __builtin_amdgcn_mfma_f32_16x16x32_bf16(af[i], bf[j], acc[i][j], 0,0,0);
  }

  #pragma unroll
  for (int i=0;i<4;i++){
    #pragma unroll
    for (int j=0;j<4;j++){
      const int gc = n0 + wn + (j<<4) + c;
      #pragma unroll
      for (int r=0;r<4;r++){
        const int gr = m0 + wm + (i<<4) + (g<<2) + r;
        const size_t idx = (size_t)gr*N + gc;
        const float vv = acc[i][j][r];
        if (EPI==EPI_BF16)      obf[idx] = f2b(vv);
        else if (EPI==EPI_WO)   of32[idx] = res[idx] + vv;
        else if (EPI==EPI_GELU) obf[idx] = f2b(gelu_t(vv + bias[gc]));
        else                    of32[idx] = of32[idx] + vv + bias[gc];
      }
    }
  }
}

// ------------- per-segment memory contribution: Mseg, zseg -------------
__global__ __launch_bounds__(256)
void memseg_k(const u16* __restrict__ kb, const u16* __restrict__ vb,
              float* __restrict__ Mseg, float* __restrict__ zseg)
{
  const int bid = blockIdx.x;           // b*64 + h*8 + seg
  const int seg = bid & 7, h = (bid>>3)&7, b = bid>>6;
  __shared__ __align__(16) u16 ks[64][136];
  __shared__ __align__(16) u16 vs[64][136];
  const int t = threadIdx.x;
  const int srow = t>>2, sc = (t&3)<<3;
  const int ty = t>>4, tx = t&15;
  float acc[8][8];
  #pragma unroll
  for (int i=0;i<8;i++)
    #pragma unroll
    for (int j=0;j<8;j++) acc[i][j]=0.f;
  float zacc = 0.f;

  for (int s0=0; s0<512; s0+=64){
    __syncthreads();
    const size_t gr = ((size_t)b*4096 + seg*512 + s0 + srow)*1024 + h*128;
    #pragma unroll
    for (int i=0;i<4;i++){
      float f[8]; unpack8(*(const uint4*)(kb + gr + sc + i*32), f);
      #pragma unroll
      for (int e=0;e<8;e++) f[e] = f[e]>0.f ? f[e]+1.f : __expf(f[e]); // elu+1
      *(uint4*)&ks[srow][sc + i*32] = pack8(f);
      *(uint4*)&vs[srow][sc + i*32] = *(const uint4*)(vb + gr + sc + i*32);
    }
    __syncthreads();
    for (int s=0;s<64;s++){
      float kf[8], vf[8];
      unpack8(*(const uint4*)&ks[s][ty<<3], kf);
      unpack8(*(const uint4*)&vs[s][tx<<3], vf);
      #pragma unroll
      for (int i=0;i<8;i++)
        #pragma unroll
        for (int j=0;j<8;j++) acc[i][j] += kf[i]*vf[j];
    }
    if (t < 128){
      for (int s=0;s<64;s++) zacc += b2f(ks[s][t]);
    }
  }
  const size_t mb = (size_t)bid*16384;
  #pragma unroll
  for (int i=0;i<8;i++)
    #pragma unroll
    for (int j=0;j<8;j++)
      Mseg[mb + (size_t)((ty<<3)+i)*128 + (tx<<3)+j] = acc[i][j];
  if (t < 128) zseg[(size_t)bid*128 + t] = zacc;
}

// --- prefix scan over segments -> memBT (TRANSPOSED [dv][kd], bf16), zB ---
__global__ __launch_bounds__(256)
void scan_k(const float* __restrict__ Mseg, const float* __restrict__ zseg,
            u16* __restrict__ memBT, float* __restrict__ zB)
{
  const int bh = blockIdx.x;   // b*8+h
  const int t = threadIdx.x;
  float run[64];
  #pragma unroll
  for (int i=0;i<64;i++) run[i]=0.f;
  for (int seg=0; seg<8; seg++){
    const size_t base = ((size_t)bh*8 + seg)*16384;
    #pragma unroll
    for (int i=0;i<64;i++){
      const int n = t + (i<<8);          // = kd*128 + dv
      const int kd = n >> 7, dv = n & 127;
      memBT[base + (size_t)dv*128 + kd] = f2b(run[i]);
    }
    #pragma unroll
    for (int i=0;i<64;i++) run[i] += Mseg[base + t + (i<<8)];
  }
  if (t < 128){
    float zr = 1.f/128.f;
    for (int seg=0; seg<8; seg++){
      const size_t base = ((size_t)bh*8 + seg)*128;
      zB[base + t] = zr;
      zr += zseg[base + t];
    }
  }
}

// ------- compressive-memory retrieval (MFMA): rmem = gate * (sq@mem)/(sq@z) -------
__global__ __launch_bounds__(256)
void retr_k(const u16* __restrict__ qb, const u16* __restrict__ memBT,
            const float* __restrict__ zB, const float* __restrict__ betas,
            u16* __restrict__ rmem)
{
  const int bid = blockIdx.x;            // b*128 + h*16 + seg*2 + half
  const int half = bid&1, seg=(bid>>1)&7, h=(bid>>4)&7, b=bid>>7;
  __shared__ __align__(16) u16 memT[128][136];
  __shared__ float zsl[128];
  const int t=threadIdx.x, w=t>>6, lane=t&63, c=lane&15, g=lane>>4;
  const size_t mbase = (((size_t)b*8+h)*8+seg)*16384;
  #pragma unroll
  for (int i=0;i<8;i++){
    const int n8 = t + (i<<8);           // 8-elem chunk index over [dv][kd]
    *(uint4*)&memT[n8>>4][(n8&15)<<3] = *(const uint4*)(memBT + mbase + ((size_t)n8<<3));
  }
  if (t<128) zsl[t] = zB[(((size_t)b*8+h)*8+seg)*128 + t];
  __syncthreads();

  bf16x8 bz[4];
  #pragma unroll
  for (int ks=0;ks<4;ks++){
    uint4 zr = {0,0,0,0};
    if (c==0) zr = pack8(&zsl[ks*32 + g*8]);
    bz[ks] = __builtin_bit_cast(bf16x8, zr);
  }
  const size_t base = ((size_t)b*4096 + seg*512)*1024 + h*128;
  const int q0 = half*256 + w*64;
  for (int qt=0; qt<4; qt++){
    const int q16 = q0 + qt*16;
    bf16x8 af[4];
    #pragma unroll
    for (int ks=0;ks<4;ks++){
      const uint4 raw = *(const uint4*)(qb + base + (size_t)(q16 + c)*1024 + ks*32 + g*8);
      float f[8]; unpack8(raw, f);
      #pragma unroll
      for (int e=0;e<8;e++) f[e] = f[e]>0.f ? f[e]+1.f : __expf(f[e]);  // elu+1
      af[ks] = __builtin_bit_cast(bf16x8, pack8(f));
    }
    f32x4 nacc[8];
    f32x4 zacc = {0.f,0.f,0.f,0.f};
    #pragma unroll
    for (int f=0;f<8;f++) nacc[f] = zacc;
    #pragma unroll
    for (int ks=0;ks<4;ks++){
      zacc = __builtin_amdgcn_mfma_f32_16x16x32_bf16(af[ks], bz[ks], zacc, 0,0,0);
      #pragma unroll
      for (int f=0;f<8;f++){
        const bf16x8 bm = *(const bf16x8*)&memT[f*16 + c][ks*32 + g*8];
        nacc[f] = __builtin_amdgcn_mfma_f32_16x16x32_bf16(af[ks], bm, nacc[f], 0,0,0);
      }
    }
    float den[4];
    #pragma unroll
    for (int r=0;r<4;r++) den[r] = 1.f / __shfl(zacc[r], lane & 48);
    #pragma unroll
    for (int f=0;f<8;f++){
      const float bv = betas[h*128 + f*16 + c];
      const float gate = 1.f/(1.f+__expf(-bv));
      #pragma unroll
      for (int r=0;r<4;r++){
        const float am = nacc[f][r] * den[r];
        rmem[base + (size_t)(q16 + g*4 + r)*1024 + f*16 + c] = f2b(gate*am);
      }
    }
  }
}

// ------------- flash local attention (MFMA) + combine with rmem -------------
__global__ __launch_bounds__(256)
void attn_k(const u16* __restrict__ qb, const u16* __restrict__ kb,
            const u16* __restrict__ vb, const u16* __restrict__ rmem,
            const float* __restrict__ betas, u16* __restrict__ attc)
{
  const int bid = blockIdx.x;   // b*512 + h*64 + seg*8 + rt
  const int rt = bid&7, seg=(bid>>3)&7, h=(bid>>6)&7, b=bid>>9;
  __shared__ __align__(16) u16 QPs[64][136];  // Q tile, then reused as P tile
  __shared__ __align__(16) u16 Ks[64][136];
  __shared__ __align__(16) u16 Vt[128][72];   // V transposed [dv][kr]
  const int t=threadIdx.x, w=t>>6, lane=t&63, c=lane&15, g=lane>>4;
  const size_t base = ((size_t)b*4096 + seg*512)*1024 + h*128;

  { // Q stage (wave-local rows: wave w stages rows 16w..16w+15)
    const int row = t>>2, c0 = (t&3)<<5;
    const u16* src = qb + base + (size_t)(rt*64+row)*1024 + c0;
    #pragma unroll
    for (int jj=0;jj<4;jj++)
      *(uint4*)&QPs[row][c0 + jj*8] = *(const uint4*)(src + jj*8);
  }
  bf16x8 af[4];
  #pragma unroll
  for (int ks=0;ks<4;ks++) af[ks] = *(const bf16x8*)&QPs[w*16 + c][ks*32 + g*8];

  f32x4 acc[8];
  #pragma unroll
  for (int f=0;f<8;f++) acc[f] = (f32x4){0.f,0.f,0.f,0.f};
  float m_run[4], l_run[4];
  #pragma unroll
  for (int r=0;r<4;r++){ m_run[r] = -1e30f; l_run[r] = 0.f; }
  const float scl = 0.08838834764831845f;

  for (int kc=0; kc<=rt; kc++){
    __syncthreads();
    { // stage K rows; stage V transposed
      const int row = t>>2, c0 = (t&3)<<5;
      const u16* ksrc = kb + base + (size_t)(kc*64+row)*1024 + c0;
      #pragma unroll
      for (int jj=0;jj<4;jj++)
        *(uint4*)&Ks[row][c0 + jj*8] = *(const uint4*)(ksrc + jj*8);
      const int kr = t & 63, d0 = (t>>6)<<5;
      const u16* vsrc = vb + base + (size_t)(kc*64+kr)*1024 + d0;
      #pragma unroll
      for (int jj=0;jj<4;jj++){
        const uint4 vv = *(const uint4*)(vsrc + jj*8);
        u16 tmp[8]; *(uint4*)tmp = vv;
        #pragma unroll
        for (int e=0;e<8;e++) Vt[d0 + jj*8 + e][kr] = tmp[e];
      }
    }
    __syncthreads();
    // QK^T: S[16q x 64kr] per wave
    f32x4 s[4];
    #pragma unroll
    for (int j=0;j<4;j++) s[j] = (f32x4){0.f,0.f,0.f,0.f};
    #pragma unroll
    for (int ks=0;ks<4;ks++)
      #pragma unroll
      for (int j=0;j<4;j++){
        const bf16x8 bk = *(const bf16x8*)&Ks[j*16 + c][ks*32 + g*8];
        s[j] = __builtin_amdgcn_mfma_f32_16x16x32_bf16(af[ks], bk, s[j], 0,0,0);
      }
    const bool diag = (kc==rt);
    float p[4][4], rm[4], rs[4];
    #pragma unroll
    for (int r=0;r<4;r++){
      float mx = -1e30f;
      #pragma unroll
      for (int j=0;j<4;j++){
        float sv = s[j][r]*scl;
        if (diag && (j*16+c) > (w*16 + g*4 + r)) sv = -1e30f;
        p[j][r] = sv;
        mx = fmaxf(mx, sv);
      }
      rm[r] = mx;
    }
    #pragma unroll
    for (int o=1;o<16;o<<=1)
      #pragma unroll
      for (int r=0;r<4;r++) rm[r] = fmaxf(rm[r], __shfl_xor(rm[r], o));
    #pragma unroll
    for (int r=0;r<4;r++){
      const float mn = fmaxf(m_run[r], rm[r]);
      const float sc = __expf(m_run[r] - mn);
      m_run[r] = mn;
      float sum = 0.f;
      #pragma unroll
      for (int j=0;j<4;j++){ p[j][r] = __expf(p[j][r]-mn); sum += p[j][r]; }
      rs[r] = sum;
      l_run[r] *= sc;
      #pragma unroll
      for (int f=0;f<8;f++) acc[f][r] *= sc;
    }
    #pragma unroll
    for (int o=1;o<16;o<<=1)
      #pragma unroll
      for (int r=0;r<4;r++) rs[r] += __shfl_xor(rs[r], o);
    #pragma unroll
    for (int r=0;r<4;r++) l_run[r] += rs[r];
    // P -> LDS (wave-local rows of QPs)
    #pragma unroll
    for (int j=0;j<4;j++)
      #pragma unroll
      for (int r=0;r<4;r++)
        QPs[w*16 + g*4 + r][j*16 + c] = f2b(p[j][r]);
    // PV
    #pragma unroll
    for (int ks2=0; ks2<2; ks2++){
      const bf16x8 pa = *(const bf16x8*)&QPs[w*16 + c][ks2*32 + g*8];
      #pragma unroll
      for (int f=0;f<8;f++){
        const bf16x8 bv = *(const bf16x8*)&Vt[f*16 + c][ks2*32 + g*8];
        acc[f] = __builtin_amdgcn_mfma_f32_16x16x32_bf16(pa, bv, acc[f], 0,0,0);
      }
    }
  }
  // epilogue: out = rmem + (1-gate)*att
  #pragma unroll
  for (int f=0;f<8;f++){
    const float bv = betas[h*128 + f*16 + c];
    const float gate = 1.f/(1.f+__expf(-bv));
    #pragma unroll
    for (int r=0;r<4;r++){
      const size_t idx = base + (size_t)(rt*64 + w*16 + g*4 + r)*1024 + f*16 + c;
      const float att = acc[f][r] / l_run[r];
      attc[idx] = f2b(b2f(rmem[idx]) + (1.f-gate)*att);
    }
  }
}

extern "C" void kernel_launch(void* const* d_in, const int* in_sizes, int n_in,
                              void* d_out, int out_size, void* d_ws, size_t ws_size,
                              hipStream_t stream)
{
  (void)in_sizes; (void)n_in; (void)out_size; (void)ws_size;
  const float* x    = (const float*)d_in[0];
  const float* ln_g = (const float*)d_in[1];
  const float* ln_b = (const float*)d_in[2];
  const float* Wq   = (const float*)d_in[3];
  const float* Wk   = (const float*)d_in[4];
  const float* Wv   = (const float*)d_in[5];
  const float* Wo   = (const float*)d_in[6];
  const float* betas= (const float*)d_in[7];
  const float* w1   = (const float*)d_in[8];
  const float* b1   = (const float*)d_in[9];
  const float* w2   = (const float*)d_in[10];
  const float* b2   = (const float*)d_in[11];
  float* out = (float*)d_out;

  // ---- workspace: 96 MB qkv + 24 MB bf16 weights = 120 MB ----
  char* ws = (char*)d_ws;
  const size_t MB = 1048576;
  u16* qb  = (u16*)(ws);              // R1: qb -> at (in-place)
  u16* kb  = (u16*)(ws + 32*MB);      // R2: kb -> h2
  u16* vb  = (u16*)(ws + 64*MB);      // R3: vb -> gb
  u16* Wqb = (u16*)(ws + 96*MB);      // [N][K] bf16 weights
  u16* Wkb = (u16*)(ws + 98*MB);
  u16* Wvb = (u16*)(ws + 100*MB);
  u16* Wob = (u16*)(ws + 102*MB);
  u16* w1b = (u16*)(ws + 104*MB);     // 8 MB
  u16* w2b = (u16*)(ws + 112*MB);     // 8 MB
  // ---- d_out doubles as scratch before the Wo GEMM overwrites it ----
  char* ob = (char*)d_out;
  u16*   h    = (u16*)ob;             // 32 MB bf16 (LN1 out; dead after QKV)
  u16*   rmem = (u16*)ob;             // then retrieval output (over h)
  float* Mseg = (float*)(ob + 32*MB); // 16 MB
  u16*   memBT= (u16*)  (ob + 48*MB); // 8 MB
  float* zseg = (float*)(ob + 56*MB); // 128 KB
  float* zB   = (float*)(ob + 56*MB + 131072);
  u16*   at   = qb;
  u16*   h2   = kb;
  u16*   gb   = vb;

  // weight conversion (fp32 [K][N] -> bf16 [N][K])
  wconv_k<<<dim3(32,32),256,0,stream>>>(Wq, Wqb, 1024,1024);
  wconv_k<<<dim3(32,32),256,0,stream>>>(Wk, Wkb, 1024,1024);
  wconv_k<<<dim3(32,32),256,0,stream>>>(Wv, Wvb, 1024,1024);
  wconv_k<<<dim3(32,32),256,0,stream>>>(Wo, Wob, 1024,1024);
  wconv_k<<<dim3(128,32),256,0,stream>>>(w1, w1b, 1024,4096);
  wconv_k<<<dim3(32,128),256,0,stream>>>(w2, w2b, 4096,1024);

  ln_k<<<16384,256,0,stream>>>(x, ln_g, ln_b, h);
  dim3 g1(8,128);
  gemm2_k<EPI_BF16><<<g1,256,0,stream>>>(h, Wqb, 1024,1024, qb, nullptr, nullptr, nullptr);
  gemm2_k<EPI_BF16><<<g1,256,0,stream>>>(h, Wkb, 1024,1024, kb, nullptr, nullptr, nullptr);
  gemm2_k<EPI_BF16><<<g1,256,0,stream>>>(h, Wvb, 1024,1024, vb, nullptr, nullptr, nullptr);
  memseg_k<<<256,256,0,stream>>>(kb, vb, Mseg, zseg);
  scan_k<<<32,256,0,stream>>>(Mseg, zseg, memBT, zB);
  retr_k<<<512,256,0,stream>>>(qb, memBT, zB, betas, rmem);   // overwrites h (dead)
  attn_k<<<2048,256,0,stream>>>(qb, kb, vb, rmem, betas, at);
  gemm2_k<EPI_WO><<<g1,256,0,stream>>>(at, Wob, 1024,1024, nullptr, out, x, nullptr);
  ln_k<<<16384,256,0,stream>>>(out, ln_g, ln_b, h2);
  // FF chunked over rows: 4 chunks of 4096 rows (hidden chunk = 32 MB bf16)
  for (int c = 0; c < 4; c++){
    const u16*  hA = h2 + (size_t)c*4096*1024;
    float*      oC = out + (size_t)c*4096*1024;
    dim3 gf1(32,32), gf2(8,32);
    gemm2_k<EPI_GELU><<<gf1,256,0,stream>>>(hA, w1b, 1024,4096, gb, nullptr, nullptr, b1);
    gemm2_k<EPI_FF2><<<gf2,256,0,stream>>>(gb, w2b, 4096,1024, nullptr, oC, nullptr, b2);
  }
}